// Round 1
// baseline (1575.304 us; speedup 1.0000x reference)
//
#include <hip/hip_runtime.h>

// DrosophilaOpticLobeCircuit: 100-step recurrent sparse circuit.
// Strategy: build target-CSR once per call (histogram + scan + fill), then
// 100 step kernels with gather-only accumulation (no atomics in hot loop).
// Layout: batch-inner [N][8] so each edge gather is one contiguous 32B read.
// steps=100 is a python scalar in the dataset; hardcoded (device-side value).

#define BLK 256
#define STEPS 100
#define NBATCH 8
static constexpr float DT_C = 0.1f;

__global__ void k_zero(int* counts, int* tm1_pos, int N) {
    int i = blockIdx.x * BLK + threadIdx.x;
    if (i < N) { counts[i] = 0; tm1_pos[i] = -1; }
}

__global__ void k_tm1pos(const int* __restrict__ tm1_idx, int* tm1_pos, int NT) {
    int i = blockIdx.x * BLK + threadIdx.x;
    if (i < NT) tm1_pos[tm1_idx[i]] = i;
}

__global__ void k_hist(const int* __restrict__ tgt, int* counts, int E) {
    int i = blockIdx.x * BLK + threadIdx.x;
    if (i < E) atomicAdd(&counts[tgt[i]], 1);
}

// per-256-chunk exclusive scan; chunk totals to bsum
__global__ void k_scan1(const int* __restrict__ counts, int* offsets, int* bsum, int N) {
    __shared__ int s[BLK];
    int tx = threadIdx.x;
    int i = blockIdx.x * BLK + tx;
    int v = (i < N) ? counts[i] : 0;
    s[tx] = v; __syncthreads();
    for (int d = 1; d < BLK; d <<= 1) {
        int t = (tx >= d) ? s[tx - d] : 0;
        __syncthreads();
        s[tx] += t;
        __syncthreads();
    }
    if (i < N) offsets[i] = s[tx] - v;       // exclusive within chunk
    if (tx == BLK - 1) bsum[blockIdx.x] = s[tx];
}

// single-block exclusive scan of chunk totals (nb <= 256)
__global__ void k_scan2(int* bsum, int nb) {
    __shared__ int s[BLK];
    int tx = threadIdx.x;
    int v = (tx < nb) ? bsum[tx] : 0;
    s[tx] = v; __syncthreads();
    for (int d = 1; d < BLK; d <<= 1) {
        int t = (tx >= d) ? s[tx - d] : 0;
        __syncthreads();
        s[tx] += t;
        __syncthreads();
    }
    if (tx < nb) bsum[tx] = s[tx] - v;
}

__global__ void k_scan3(const int* __restrict__ bsum, int* offsets, int* cursor, int N, int E) {
    int i = blockIdx.x * BLK + threadIdx.x;
    if (i < N) {
        int o = offsets[i] + bsum[i >> 8];
        offsets[i] = o;
        cursor[i] = o;
    } else if (i == N) {
        offsets[N] = E;
    }
}

__global__ void k_fill(const int* __restrict__ srcI, const int* __restrict__ tgtI,
                       const float* __restrict__ w,
                       const float* __restrict__ se, const float* __restrict__ si,
                       int* cursor, int2* __restrict__ csr, int E) {
    int i = blockIdx.x * BLK + threadIdx.x;
    if (i >= E) return;
    float wv = w[i];
    float sc = wv > 0.f ? se[0] : (wv < 0.f ? si[0] : 1.f);
    float sw = wv * sc;
    int t = tgtI[i];
    int pos = atomicAdd(&cursor[t], 1);
    csr[pos] = make_int2(srcI[i], __float_as_int(sw));
}

// init v_work[N][8], r0=r1=relu(v), per-neuron coefficients
__global__ void k_initv(const float* __restrict__ tm1_in, const float* __restrict__ v_init,
                        const float* __restrict__ bias, const float* __restrict__ tau_p,
                        const int* __restrict__ type_ids, const int* __restrict__ tm1_pos,
                        float* __restrict__ v_w, float* __restrict__ r0, float* __restrict__ r1,
                        float4* __restrict__ coef, int N, int NT) {
    int n = blockIdx.x * BLK + threadIdx.x;
    if (n >= N) return;
    int k = tm1_pos[n];
    float tau = tau_p[type_ids[n]];
    float g = DT_C / tau;
    coef[n] = make_float4(1.f - g, g, bias[n] * g, (k >= 0) ? 1.f : 0.f);
    float vv[NBATCH], rr[NBATCH];
    for (int b = 0; b < NBATCH; ++b) {
        float val = (k >= 0) ? tm1_in[b * NT + k] : v_init[b * N + n];
        vv[b] = val;
        rr[b] = fmaxf(val, 0.f);
    }
    float4* vp = (float4*)(v_w + (size_t)n * 8);
    float4* r0p = (float4*)(r0 + (size_t)n * 8);
    float4* r1p = (float4*)(r1 + (size_t)n * 8);
    vp[0]  = make_float4(vv[0], vv[1], vv[2], vv[3]);
    vp[1]  = make_float4(vv[4], vv[5], vv[6], vv[7]);
    float4 rlo = make_float4(rr[0], rr[1], rr[2], rr[3]);
    float4 rhi = make_float4(rr[4], rr[5], rr[6], rr[7]);
    r0p[0] = rlo; r0p[1] = rhi;
    r1p[0] = rlo; r1p[1] = rhi;
}

// one 8-lane group per target neuron; lane `sub` strides edges, 8 batch
// partials in registers, then butterfly transpose-reduce so lane j holds
// batch j; coalesced 256B wave store of v_new / relu(v_new).
__global__ __launch_bounds__(BLK) void k_step(
        const int* __restrict__ offsets, const int2* __restrict__ csr,
        const float4* __restrict__ coef, const float* __restrict__ r_prev,
        float* __restrict__ v_w, float* __restrict__ r_next, int N) {
    int tid = blockIdx.x * BLK + threadIdx.x;
    int n = tid >> 3;
    int sub = threadIdx.x & 7;
    if (n >= N) return;
    float4 cf = coef[n];
    if (cf.w != 0.f) return;                 // Tm1 row: clamped, dv=0, r constant
    int s = offsets[n], e = offsets[n + 1];
    float4 a0 = make_float4(0.f, 0.f, 0.f, 0.f);
    float4 a1 = make_float4(0.f, 0.f, 0.f, 0.f);
    for (int i = s + sub; i < e; i += 8) {
        int2 ew = csr[i];
        float w = __int_as_float(ew.y);
        const float4* rp = (const float4*)(r_prev + (size_t)ew.x * 8);
        float4 ra = rp[0], rb = rp[1];
        a0.x += w * ra.x; a0.y += w * ra.y; a0.z += w * ra.z; a0.w += w * ra.w;
        a1.x += w * rb.x; a1.y += w * rb.y; a1.z += w * rb.z; a1.w += w * rb.w;
    }
    int bit0 = sub & 1, bit1 = (sub >> 1) & 1, bit2 = (sub >> 2) & 1;
    // stage 1 (xor 1): keep batches with bit0 == lane bit0
    float b0 = (bit0 ? a0.y : a0.x) + __shfl_xor(bit0 ? a0.x : a0.y, 1);
    float b1 = (bit0 ? a0.w : a0.z) + __shfl_xor(bit0 ? a0.z : a0.w, 1);
    float b2 = (bit0 ? a1.y : a1.x) + __shfl_xor(bit0 ? a1.x : a1.y, 1);
    float b3 = (bit0 ? a1.w : a1.z) + __shfl_xor(bit0 ? a1.z : a1.w, 1);
    // stage 2 (xor 2)
    float c0 = (bit1 ? b1 : b0) + __shfl_xor(bit1 ? b0 : b1, 2);
    float c1 = (bit1 ? b3 : b2) + __shfl_xor(bit1 ? b2 : b3, 2);
    // stage 3 (xor 4): lane sub now holds full sum for batch==sub
    float syn = (bit2 ? c1 : c0) + __shfl_xor(bit2 ? c0 : c1, 4);
    size_t idx = (size_t)n * 8 + sub;
    float vo = v_w[idx];
    float vn = vo * cf.x + syn * cf.y + cf.z;
    v_w[idx] = vn;
    r_next[idx] = fmaxf(vn, 0.f);
}

__global__ void k_out(const float* __restrict__ v_w, float* __restrict__ out, int N) {
    int t = blockIdx.x * BLK + threadIdx.x;
    if (t >= NBATCH * N) return;
    int b = t / N;
    int n = t - b * N;
    out[t] = v_w[(size_t)n * 8 + b];
}

static inline size_t align16(size_t x) { return (x + 15) & ~(size_t)15; }

extern "C" void kernel_launch(void* const* d_in, const int* in_sizes, int n_in,
                              void* d_out, int out_size, void* d_ws, size_t ws_size,
                              hipStream_t stream) {
    const float* tm1_in  = (const float*)d_in[0];
    const float* v_init  = (const float*)d_in[1];
    const float* weights = (const float*)d_in[2];
    const float* bias    = (const float*)d_in[3];
    const float* tau_p   = (const float*)d_in[4];
    const float* se      = (const float*)d_in[5];
    const float* si      = (const float*)d_in[6];
    const int*   srcI    = (const int*)d_in[7];
    const int*   tgtI    = (const int*)d_in[8];
    const int*   type_ids= (const int*)d_in[9];
    const int*   tm1_idx = (const int*)d_in[10];

    const int E  = in_sizes[2];
    const int N  = in_sizes[3];
    const int NT = in_sizes[10];

    // workspace carve-up (16B aligned regions)
    char* p = (char*)d_ws;
    size_t off = 0;
    auto take = [&](size_t bytes) { void* r = p + off; off += align16(bytes); return r; };
    int*    offsets = (int*)   take((size_t)(N + 1) * 4);
    int*    cursor  = (int*)   take((size_t)N * 4);
    int*    counts  = (int*)   take((size_t)N * 4);
    int*    tm1_pos = (int*)   take((size_t)N * 4);
    int*    bsum    = (int*)   take(1024 * 4);
    int2*   csr     = (int2*)  take((size_t)E * 8);
    float4* coef    = (float4*)take((size_t)N * 16);
    float*  v_w     = (float*) take((size_t)N * 8 * 4);
    float*  r0      = (float*) take((size_t)N * 8 * 4);
    float*  r1      = (float*) take((size_t)N * 8 * 4);
    (void)ws_size;

    const int gN  = (N + BLK - 1) / BLK;
    const int gN1 = (N + 1 + BLK - 1) / BLK;
    const int gE  = (E + BLK - 1) / BLK;
    const int gNT = (NT + BLK - 1) / BLK;
    const int gS  = (N * NBATCH + BLK - 1) / BLK;

    k_zero<<<gN, BLK, 0, stream>>>(counts, tm1_pos, N);
    k_tm1pos<<<gNT, BLK, 0, stream>>>(tm1_idx, tm1_pos, NT);
    k_hist<<<gE, BLK, 0, stream>>>(tgtI, counts, E);
    k_scan1<<<gN, BLK, 0, stream>>>(counts, offsets, bsum, N);
    k_scan2<<<1, BLK, 0, stream>>>(bsum, gN);
    k_scan3<<<gN1, BLK, 0, stream>>>(bsum, offsets, cursor, N, E);
    k_fill<<<gE, BLK, 0, stream>>>(srcI, tgtI, weights, se, si, cursor, csr, E);
    k_initv<<<gN, BLK, 0, stream>>>(tm1_in, v_init, bias, tau_p, type_ids, tm1_pos,
                                    v_w, r0, r1, coef, N, NT);

    float* rb[2] = { r0, r1 };
    for (int s = 0; s < STEPS; ++s) {
        k_step<<<gS, BLK, 0, stream>>>(offsets, csr, coef, rb[s & 1],
                                       v_w, rb[(s + 1) & 1], N);
    }
    k_out<<<gS, BLK, 0, stream>>>(v_w, (float*)d_out, N);
}